// Round 2
// baseline (559.989 us; speedup 1.0000x reference)
//
#include <hip/hip_runtime.h>
#include <stdint.h>

#define NB 32      // batch
#define NC 32      // in channels
#define NN 1024    // nodes
#define NT 12      // time
#define NJ (NB*NC*NT)  // 12288
#define NO 32      // out channels
#define TIN 224    // (2*3+1)*32

typedef __attribute__((ext_vector_type(8))) __bf16 bf16x8;
typedef __attribute__((ext_vector_type(4))) float f32x4;
typedef unsigned short u16;
typedef unsigned int u32;

__device__ __forceinline__ u16 f2bf(float f){
  u32 u = __float_as_uint(f);
  u32 r = (u + 0x7FFFu + ((u >> 16) & 1u)) >> 16;   // RNE
  return (u16)r;
}
__device__ __forceinline__ float bf2f(u16 h){
  return __uint_as_float(((u32)h) << 16);
}

typedef const __attribute__((address_space(1))) u32* gp_t;
typedef __attribute__((address_space(3))) u32* lp_t;
__device__ __forceinline__ void gll16(const void* g, void* l){
  __builtin_amdgcn_global_load_lds((gp_t)g, (lp_t)l, 16, 0, 0);
}

// ---------- prep adj: At[z][m][n] = bf16(adj_z[n][m]) ----------
__global__ __launch_bounds__(256) void k_prep_adj(const float* __restrict__ a0,
      const float* __restrict__ a1, const float* __restrict__ a2, u16* __restrict__ At){
  __shared__ float tile[32][33];
  const float* A = (blockIdx.z==0) ? a0 : (blockIdx.z==1 ? a1 : a2);
  int n0 = blockIdx.x*32, m0 = blockIdx.y*32;
  int tx = threadIdx.x, ty = threadIdx.y;  // block (32,8)
  #pragma unroll
  for (int r=0;r<4;r++)
    tile[ty + 8*r][tx] = A[(size_t)(n0 + ty + 8*r)*NN + m0 + tx];
  __syncthreads();
  u16* dst = At + (size_t)blockIdx.z*NN*NN;
  #pragma unroll
  for (int r=0;r<4;r++)
    dst[(size_t)(m0 + ty + 8*r)*NN + n0 + tx] = f2bf(tile[tx][ty + 8*r]);
}

// ---------- prep x (coalesced): Zt[j][n] = bf16(x[p,n,t]), j = p*12+t ----------
__global__ __launch_bounds__(256) void k_prep_x2(const float* __restrict__ x, u16* __restrict__ Zt){
  __shared__ float tl[64][13];
  int p = blockIdx.y, n0 = blockIdx.x*64;
  const float* xp = x + (size_t)p*NN*NT + (size_t)n0*NT; // 768 consecutive floats
  int tid = threadIdx.x;
  #pragma unroll
  for (int k=0;k<3;k++){
    int e = tid + k*256;
    float v = xp[e];
    tl[e/12][e%12] = v;
  }
  __syncthreads();
  #pragma unroll
  for (int k=0;k<3;k++){
    int e = tid + k*256;
    int t = e >> 6, nn = e & 63;
    Zt[((size_t)p*NT + t)*NN + n0 + nn] = f2bf(tl[nn][t]);
  }
}

// ---------- GEMM: Out[j][m] = sum_k Amat[m][k] * Bmat[j][k] ----------
#define BKK 64
__global__ __launch_bounds__(256) void k_gemm(const u16* __restrict__ Amat,
                                              const u16* __restrict__ Bmat,
                                              u16* __restrict__ Out){
  __shared__ __align__(16) u16 As[128*BKK];
  __shared__ __align__(16) u16 Bs[128*BKK];
  int tid = threadIdx.x;
  int w = tid >> 6, lane = tid & 63;
  int m0 = blockIdx.y * 128, j0 = blockIdx.x * 128;
  int wr = w >> 1, wc = w & 1;
  int lrow = lane & 15, kgrp = lane >> 4;
  int lr8 = lane >> 3, lc8 = lane & 7;

  f32x4 acc[4][4];
  #pragma unroll
  for (int i=0;i<4;i++)
    #pragma unroll
    for (int jj=0;jj<4;jj++)
      acc[i][jj] = (f32x4){0.f,0.f,0.f,0.f};

  const u16* Abase = Amat + (size_t)m0*1024;
  const u16* Bbase = Bmat + (size_t)j0*1024;

  for (int kt=0; kt<1024/BKK; ++kt){
    int k0 = kt*BKK;
    #pragma unroll
    for (int i=0;i<4;i++){
      int q = w*4 + i;
      int row = q*8 + lr8;
      gll16(Abase + (size_t)row*1024 + k0 + lc8*8, (u16*)As + q*512);
      gll16(Bbase + (size_t)row*1024 + k0 + lc8*8, (u16*)Bs + q*512);
    }
    __syncthreads();
    #pragma unroll
    for (int kk=0; kk<2; ++kk){
      bf16x8 af[4], bfr[4];
      #pragma unroll
      for (int mi=0;mi<4;mi++)
        af[mi] = *reinterpret_cast<const bf16x8*>(&As[(wr*64+mi*16+lrow)*BKK + kk*32 + kgrp*8]);
      #pragma unroll
      for (int ji=0;ji<4;ji++)
        bfr[ji] = *reinterpret_cast<const bf16x8*>(&Bs[(wc*64+ji*16+lrow)*BKK + kk*32 + kgrp*8]);
      #pragma unroll
      for (int mi=0;mi<4;mi++)
        #pragma unroll
        for (int ji=0;ji<4;ji++)
          acc[mi][ji] = __builtin_amdgcn_mfma_f32_16x16x32_bf16(af[mi], bfr[ji], acc[mi][ji], 0, 0, 0);
    }
    __syncthreads();
  }

  #pragma unroll
  for (int mi=0;mi<4;mi++){
    #pragma unroll
    for (int ji=0;ji<4;ji++){
      int jg = j0 + wc*64 + ji*16 + lrow;
      int mg = m0 + wr*64 + mi*16 + kgrp*4;
      ushort4 st;
      st.x = f2bf(acc[mi][ji][0]);
      st.y = f2bf(acc[mi][ji][1]);
      st.z = f2bf(acc[mi][ji][2]);
      st.w = f2bf(acc[mi][ji][3]);
      *reinterpret_cast<ushort4*>(&Out[(size_t)jg*1024 + mg]) = st;
    }
  }
}

// ---------- coalesced channel-mix accumulation ----------
// thread = (b, n-pair, og): acc[4 o][12 t][2 n]; y accesses are 96B-contiguous.
template<int NG>
__global__ __launch_bounds__(256) void k_accum2(const float* __restrict__ x,
    const u16* __restrict__ h1_0, const u16* __restrict__ h2_0,
    const u16* __restrict__ h1_1, const u16* __restrict__ h2_1,
    const u16* __restrict__ h1_2, const u16* __restrict__ h2_2,
    const float* __restrict__ W, const float* __restrict__ bias,
    float* __restrict__ y, int g0, int first){
  int tid = threadIdx.x;
  int p = tid & 31, og = tid >> 5;           // 32 n-pairs x 8 o-groups
  int n = blockIdx.x*64 + 2*p;
  int b = blockIdx.y;
  float acc[4][12][2];

  if (first){
    #pragma unroll
    for (int oo=0;oo<4;oo++){
      float bv = bias[og*4+oo];
      #pragma unroll
      for (int t=0;t<12;t++){ acc[oo][t][0]=bv; acc[oo][t][1]=bv; }
    }
    for (int c=0;c<NC;c++){
      float wx[4];
      #pragma unroll
      for (int oo=0;oo<4;oo++) wx[oo] = W[(size_t)(og*4+oo)*TIN + c];
      const float4* xp = (const float4*)(x + ((size_t)(b*NC+c)*NN + n)*NT);
      float4 xv[6];
      #pragma unroll
      for (int q=0;q<6;q++) xv[q] = xp[q];
      const float* xs = (const float*)xv;
      #pragma unroll
      for (int t=0;t<12;t++){
        #pragma unroll
        for (int oo=0;oo<4;oo++){
          acc[oo][t][0] += wx[oo]*xs[t];
          acc[oo][t][1] += wx[oo]*xs[12+t];
        }
      }
    }
  } else {
    #pragma unroll
    for (int oo=0;oo<4;oo++){
      const float4* yp = (const float4*)(y + ((size_t)(b*NO+og*4+oo)*NN + n)*NT);
      float4 yv[6];
      #pragma unroll
      for (int q=0;q<6;q++) yv[q] = yp[q];
      const float* ys = (const float*)yv;
      #pragma unroll
      for (int t=0;t<12;t++){ acc[oo][t][0]=ys[t]; acc[oo][t][1]=ys[12+t]; }
    }
  }

  #pragma unroll
  for (int gg=0; gg<NG; ++gg){
    const u16* h1p; const u16* h2p; int g;
    if (NG==1){ h1p=h1_0; h2p=h2_0; g=g0; }
    else { g=gg; h1p = gg==0?h1_0:(gg==1?h1_1:h1_2); h2p = gg==0?h2_0:(gg==1?h2_1:h2_2); }
    int gb = (1+2*g)*32;
    for (int c=0;c<NC;c++){
      float w1[4], w2[4];
      #pragma unroll
      for (int oo=0;oo<4;oo++){
        w1[oo] = W[(size_t)(og*4+oo)*TIN + gb + c];
        w2[oo] = W[(size_t)(og*4+oo)*TIN + gb + 32 + c];
      }
      size_t rbase = ((size_t)(b*NC+c)*NT)*NN + n;
      #pragma unroll
      for (int t=0;t<12;t++){
        u32 v1 = *(const u32*)(h1p + rbase + (size_t)t*NN);
        u32 v2 = *(const u32*)(h2p + rbase + (size_t)t*NN);
        float h1a = bf2f((u16)(v1&0xFFFFu)), h1b = bf2f((u16)(v1>>16));
        float h2a = bf2f((u16)(v2&0xFFFFu)), h2b = bf2f((u16)(v2>>16));
        #pragma unroll
        for (int oo=0;oo<4;oo++){
          acc[oo][t][0] += w1[oo]*h1a + w2[oo]*h2a;
          acc[oo][t][1] += w1[oo]*h1b + w2[oo]*h2b;
        }
      }
    }
  }

  #pragma unroll
  for (int oo=0;oo<4;oo++){
    float4* yp = (float4*)(y + ((size_t)(b*NO+og*4+oo)*NN + n)*NT);
    float4 outv[6];
    float* os = (float*)outv;
    #pragma unroll
    for (int t=0;t<12;t++){ os[t]=acc[oo][t][0]; os[12+t]=acc[oo][t][1]; }
    #pragma unroll
    for (int q=0;q<6;q++) yp[q] = outv[q];
  }
}

extern "C" void kernel_launch(void* const* d_in, const int* in_sizes, int n_in,
                              void* d_out, int out_size, void* d_ws, size_t ws_size,
                              hipStream_t stream){
  const float* x    = (const float*)d_in[0];
  const float* a0   = (const float*)d_in[1];
  const float* a1   = (const float*)d_in[2];
  const float* a2   = (const float*)d_in[3];
  const float* W    = (const float*)d_in[4];
  const float* bias = (const float*)d_in[5];
  float* y = (float*)d_out;
  (void)in_sizes; (void)n_in; (void)out_size;

  const size_t atB = (size_t)3*NN*NN*2;     // 6 MB
  const size_t hB  = (size_t)NJ*NN*2;       // 25.2 MB each
  const size_t need_fused = atB + 7*hB;     // At + Zt + 6 H  (~182 MB)

  char* ws = (char*)d_ws;
  u16* At = (u16*)ws;  ws += atB;
  u16* Zt = (u16*)ws;  ws += hB;

  k_prep_adj<<<dim3(32,32,3), dim3(32,8), 0, stream>>>(a0, a1, a2, At);
  k_prep_x2 <<<dim3(NN/64, NB*NC), 256, 0, stream>>>(x, Zt);

  if (ws_size >= need_fused){
    u16* H1[3]; u16* H2[3];
    for (int g=0; g<3; ++g){ H1[g]=(u16*)ws; ws+=hB; H2[g]=(u16*)ws; ws+=hB; }
    for (int g=0; g<3; ++g){
      const u16* Ag = At + (size_t)g*NN*NN;
      k_gemm<<<dim3(NJ/128, NN/128), 256, 0, stream>>>(Ag, Zt, H1[g]);
      k_gemm<<<dim3(NJ/128, NN/128), 256, 0, stream>>>(Ag, H1[g], H2[g]);
    }
    k_accum2<3><<<dim3(NN/64, NB), 256, 0, stream>>>(x, H1[0],H2[0],H1[1],H2[1],H1[2],H2[2],
                                                     W, bias, y, 0, 1);
  } else {
    u16* H1 = (u16*)ws;  ws += hB;
    u16* H2 = (u16*)ws;  ws += hB;
    for (int g=0; g<3; ++g){
      const u16* Ag = At + (size_t)g*NN*NN;
      k_gemm<<<dim3(NJ/128, NN/128), 256, 0, stream>>>(Ag, Zt, H1);
      k_gemm<<<dim3(NJ/128, NN/128), 256, 0, stream>>>(Ag, H1, H2);
      k_accum2<1><<<dim3(NN/64, NB), 256, 0, stream>>>(x, H1,H2,H1,H2,H1,H2,
                                                       W, bias, y, g, g==0 ? 1 : 0);
    }
  }
}

// Round 3
// 559.567 us; speedup vs baseline: 1.0008x; 1.0008x over previous
//
#include <hip/hip_runtime.h>
#include <stdint.h>

#define NB 32      // batch
#define NC 32      // in channels
#define NN 1024    // nodes
#define NT 12      // time
#define NJ (NB*NC*NT)  // 12288
#define NO 32      // out channels
#define TIN 224    // (2*3+1)*32

typedef __attribute__((ext_vector_type(8))) __bf16 bf16x8;
typedef __attribute__((ext_vector_type(4))) float f32x4;
typedef unsigned short u16;
typedef unsigned int u32;

__device__ __forceinline__ u16 f2bf(float f){
  u32 u = __float_as_uint(f);
  u32 r = (u + 0x7FFFu + ((u >> 16) & 1u)) >> 16;   // RNE
  return (u16)r;
}
__device__ __forceinline__ float bf2f(u16 h){
  return __uint_as_float(((u32)h) << 16);
}

typedef const __attribute__((address_space(1))) u32* gp_t;
typedef __attribute__((address_space(3))) u32* lp_t;
__device__ __forceinline__ void gll16(const void* g, void* l){
  __builtin_amdgcn_global_load_lds((gp_t)g, (lp_t)l, 16, 0, 0);
}

// ---------- prep adj: At[z][m][n] = bf16(adj_z[n][m]) ----------
__global__ __launch_bounds__(256) void k_prep_adj(const float* __restrict__ a0,
      const float* __restrict__ a1, const float* __restrict__ a2, u16* __restrict__ At){
  __shared__ float tile[32][33];
  const float* A = (blockIdx.z==0) ? a0 : (blockIdx.z==1 ? a1 : a2);
  int n0 = blockIdx.x*32, m0 = blockIdx.y*32;
  int tx = threadIdx.x, ty = threadIdx.y;  // block (32,8)
  #pragma unroll
  for (int r=0;r<4;r++)
    tile[ty + 8*r][tx] = A[(size_t)(n0 + ty + 8*r)*NN + m0 + tx];
  __syncthreads();
  u16* dst = At + (size_t)blockIdx.z*NN*NN;
  #pragma unroll
  for (int r=0;r<4;r++)
    dst[(size_t)(m0 + ty + 8*r)*NN + n0 + tx] = f2bf(tile[tx][ty + 8*r]);
}

// ---------- prep x (coalesced): Zt[j][n] = bf16(x[p,n,t]), j = p*12+t ----------
__global__ __launch_bounds__(256) void k_prep_x2(const float* __restrict__ x, u16* __restrict__ Zt){
  __shared__ float tl[64][13];
  int p = blockIdx.y, n0 = blockIdx.x*64;
  const float* xp = x + (size_t)p*NN*NT + (size_t)n0*NT; // 768 consecutive floats
  int tid = threadIdx.x;
  #pragma unroll
  for (int k=0;k<3;k++){
    int e = tid + k*256;
    float v = xp[e];
    tl[e/12][e%12] = v;
  }
  __syncthreads();
  #pragma unroll
  for (int k=0;k<3;k++){
    int e = tid + k*256;
    int t = e >> 6, nn = e & 63;
    Zt[((size_t)p*NT + t)*NN + n0 + nn] = f2bf(tl[nn][t]);
  }
}

// ---------- GEMM: Out[j][m] = sum_k Amat[m][k] * Bmat[j][k] ----------
#define BKK 64
__global__ __launch_bounds__(256) void k_gemm(const u16* __restrict__ Amat,
                                              const u16* __restrict__ Bmat,
                                              u16* __restrict__ Out){
  __shared__ __align__(16) u16 As[128*BKK];
  __shared__ __align__(16) u16 Bs[128*BKK];
  int tid = threadIdx.x;
  int w = tid >> 6, lane = tid & 63;
  int m0 = blockIdx.y * 128, j0 = blockIdx.x * 128;
  int wr = w >> 1, wc = w & 1;
  int lrow = lane & 15, kgrp = lane >> 4;
  int lr8 = lane >> 3, lc8 = lane & 7;

  f32x4 acc[4][4];
  #pragma unroll
  for (int i=0;i<4;i++)
    #pragma unroll
    for (int jj=0;jj<4;jj++)
      acc[i][jj] = (f32x4){0.f,0.f,0.f,0.f};

  const u16* Abase = Amat + (size_t)m0*1024;
  const u16* Bbase = Bmat + (size_t)j0*1024;

  for (int kt=0; kt<1024/BKK; ++kt){
    int k0 = kt*BKK;
    #pragma unroll
    for (int i=0;i<4;i++){
      int q = w*4 + i;
      int row = q*8 + lr8;
      gll16(Abase + (size_t)row*1024 + k0 + lc8*8, (u16*)As + q*512);
      gll16(Bbase + (size_t)row*1024 + k0 + lc8*8, (u16*)Bs + q*512);
    }
    __syncthreads();
    #pragma unroll
    for (int kk=0; kk<2; ++kk){
      bf16x8 af[4], bfr[4];
      #pragma unroll
      for (int mi=0;mi<4;mi++)
        af[mi] = *reinterpret_cast<const bf16x8*>(&As[(wr*64+mi*16+lrow)*BKK + kk*32 + kgrp*8]);
      #pragma unroll
      for (int ji=0;ji<4;ji++)
        bfr[ji] = *reinterpret_cast<const bf16x8*>(&Bs[(wc*64+ji*16+lrow)*BKK + kk*32 + kgrp*8]);
      #pragma unroll
      for (int mi=0;mi<4;mi++)
        #pragma unroll
        for (int ji=0;ji<4;ji++)
          acc[mi][ji] = __builtin_amdgcn_mfma_f32_16x16x32_bf16(af[mi], bfr[ji], acc[mi][ji], 0, 0, 0);
    }
    __syncthreads();
  }

  #pragma unroll
  for (int mi=0;mi<4;mi++){
    #pragma unroll
    for (int ji=0;ji<4;ji++){
      int jg = j0 + wc*64 + ji*16 + lrow;
      int mg = m0 + wr*64 + mi*16 + kgrp*4;
      ushort4 st;
      st.x = f2bf(acc[mi][ji][0]);
      st.y = f2bf(acc[mi][ji][1]);
      st.z = f2bf(acc[mi][ji][2]);
      st.w = f2bf(acc[mi][ji][3]);
      *reinterpret_cast<ushort4*>(&Out[(size_t)jg*1024 + mg]) = st;
    }
  }
}

// ---------- coalesced channel-mix accumulation (NO pointer aliasing!) ----------
// thread = (b, n-pair, og): acc[4 o][12 t][2 n] in REGISTERS; y accesses are
// 96B-contiguous float4 bursts. All acc/array indices are compile-time.
template<int NG>
__global__ __launch_bounds__(256) void k_accum2(const float* __restrict__ x,
    const u16* __restrict__ h1_0, const u16* __restrict__ h2_0,
    const u16* __restrict__ h1_1, const u16* __restrict__ h2_1,
    const u16* __restrict__ h1_2, const u16* __restrict__ h2_2,
    const float* __restrict__ W, const float* __restrict__ bias,
    float* __restrict__ y, int g0, int first){
  int tid = threadIdx.x;
  int p = tid & 31, og = tid >> 5;           // 32 n-pairs x 8 o-groups
  int n = blockIdx.x*64 + 2*p;
  int b = blockIdx.y;
  float acc[4][12][2];

  if (first){
    #pragma unroll
    for (int oo=0;oo<4;oo++){
      float bv = bias[og*4+oo];
      #pragma unroll
      for (int t=0;t<12;t++){ acc[oo][t][0]=bv; acc[oo][t][1]=bv; }
    }
    for (int c=0;c<NC;c++){
      float wx[4];
      #pragma unroll
      for (int oo=0;oo<4;oo++) wx[oo] = W[(size_t)(og*4+oo)*TIN + c];
      const float4* xp = (const float4*)(x + ((size_t)(b*NC+c)*NN + n)*NT);
      float xs[24];
      #pragma unroll
      for (int q=0;q<6;q++){
        float4 v = xp[q];
        xs[q*4+0]=v.x; xs[q*4+1]=v.y; xs[q*4+2]=v.z; xs[q*4+3]=v.w;
      }
      #pragma unroll
      for (int t=0;t<12;t++){
        #pragma unroll
        for (int oo=0;oo<4;oo++){
          acc[oo][t][0] += wx[oo]*xs[t];
          acc[oo][t][1] += wx[oo]*xs[12+t];
        }
      }
    }
  } else {
    #pragma unroll
    for (int oo=0;oo<4;oo++){
      const float4* yp = (const float4*)(y + ((size_t)(b*NO+og*4+oo)*NN + n)*NT);
      float ys[24];
      #pragma unroll
      for (int q=0;q<6;q++){
        float4 v = yp[q];
        ys[q*4+0]=v.x; ys[q*4+1]=v.y; ys[q*4+2]=v.z; ys[q*4+3]=v.w;
      }
      #pragma unroll
      for (int t=0;t<12;t++){ acc[oo][t][0]=ys[t]; acc[oo][t][1]=ys[12+t]; }
    }
  }

  #pragma unroll
  for (int gg=0; gg<NG; ++gg){
    const u16* h1p; const u16* h2p; int g;
    if (NG==1){ h1p=h1_0; h2p=h2_0; g=g0; }
    else { g=gg; h1p = gg==0?h1_0:(gg==1?h1_1:h1_2); h2p = gg==0?h2_0:(gg==1?h2_1:h2_2); }
    int gb = (1+2*g)*32;
    for (int c=0;c<NC;c++){
      float w1[4], w2[4];
      #pragma unroll
      for (int oo=0;oo<4;oo++){
        w1[oo] = W[(size_t)(og*4+oo)*TIN + gb + c];
        w2[oo] = W[(size_t)(og*4+oo)*TIN + gb + 32 + c];
      }
      size_t rbase = ((size_t)(b*NC+c)*NT)*NN + n;
      #pragma unroll
      for (int t=0;t<12;t++){
        u32 v1 = *(const u32*)(h1p + rbase + (size_t)t*NN);
        u32 v2 = *(const u32*)(h2p + rbase + (size_t)t*NN);
        float h1a = bf2f((u16)(v1&0xFFFFu)), h1b = bf2f((u16)(v1>>16));
        float h2a = bf2f((u16)(v2&0xFFFFu)), h2b = bf2f((u16)(v2>>16));
        #pragma unroll
        for (int oo=0;oo<4;oo++){
          acc[oo][t][0] += w1[oo]*h1a + w2[oo]*h2a;
          acc[oo][t][1] += w1[oo]*h1b + w2[oo]*h2b;
        }
      }
    }
  }

  #pragma unroll
  for (int oo=0;oo<4;oo++){
    float4* yp = (float4*)(y + ((size_t)(b*NO+og*4+oo)*NN + n)*NT);
    #pragma unroll
    for (int q=0;q<6;q++){
      float4 v;
      v.x = acc[oo][(q*4+0)%12][(q*4+0)/12];
      v.y = acc[oo][(q*4+1)%12][(q*4+1)/12];
      v.z = acc[oo][(q*4+2)%12][(q*4+2)/12];
      v.w = acc[oo][(q*4+3)%12][(q*4+3)/12];
      yp[q] = v;
    }
  }
}

extern "C" void kernel_launch(void* const* d_in, const int* in_sizes, int n_in,
                              void* d_out, int out_size, void* d_ws, size_t ws_size,
                              hipStream_t stream){
  const float* x    = (const float*)d_in[0];
  const float* a0   = (const float*)d_in[1];
  const float* a1   = (const float*)d_in[2];
  const float* a2   = (const float*)d_in[3];
  const float* W    = (const float*)d_in[4];
  const float* bias = (const float*)d_in[5];
  float* y = (float*)d_out;
  (void)in_sizes; (void)n_in; (void)out_size;

  const size_t atB = (size_t)3*NN*NN*2;     // 6 MB
  const size_t hB  = (size_t)NJ*NN*2;       // 25.2 MB each
  const size_t need_fused = atB + 7*hB;     // At + Zt + 6 H  (~182 MB)

  char* ws = (char*)d_ws;
  u16* At = (u16*)ws;  ws += atB;
  u16* Zt = (u16*)ws;  ws += hB;

  k_prep_adj<<<dim3(32,32,3), dim3(32,8), 0, stream>>>(a0, a1, a2, At);
  k_prep_x2 <<<dim3(NN/64, NB*NC), 256, 0, stream>>>(x, Zt);

  if (ws_size >= need_fused){
    u16* H1[3]; u16* H2[3];
    for (int g=0; g<3; ++g){ H1[g]=(u16*)ws; ws+=hB; H2[g]=(u16*)ws; ws+=hB; }
    for (int g=0; g<3; ++g){
      const u16* Ag = At + (size_t)g*NN*NN;
      k_gemm<<<dim3(NJ/128, NN/128), 256, 0, stream>>>(Ag, Zt, H1[g]);
      k_gemm<<<dim3(NJ/128, NN/128), 256, 0, stream>>>(Ag, H1[g], H2[g]);
    }
    k_accum2<3><<<dim3(NN/64, NB), 256, 0, stream>>>(x, H1[0],H2[0],H1[1],H2[1],H1[2],H2[2],
                                                     W, bias, y, 0, 1);
  } else {
    u16* H1 = (u16*)ws;  ws += hB;
    u16* H2 = (u16*)ws;  ws += hB;
    for (int g=0; g<3; ++g){
      const u16* Ag = At + (size_t)g*NN*NN;
      k_gemm<<<dim3(NJ/128, NN/128), 256, 0, stream>>>(Ag, Zt, H1);
      k_gemm<<<dim3(NJ/128, NN/128), 256, 0, stream>>>(Ag, H1, H2);
      k_accum2<1><<<dim3(NN/64, NB), 256, 0, stream>>>(x, H1,H2,H1,H2,H1,H2,
                                                       W, bias, y, g, g==0 ? 1 : 0);
    }
  }
}